// Round 9
// baseline (605.032 us; speedup 1.0000x reference)
//
#include <hip/hip_runtime.h>

#define NN 50000
#define NE 800000
#define DD 256
#define CC 8
#define HH 64
#define CHW 512   // C*H
#define LN_EPS 1e-5f
#define SCAN_BLOCKS ((NN + 1023) / 1024)  // 49

typedef __attribute__((ext_vector_type(8))) __bf16 bf16x8;
typedef __attribute__((ext_vector_type(4))) float f32x4;

// round-to-nearest-even f32 -> bf16 (values are finite here)
__device__ inline ushort f2bf(float f) {
  uint u = __float_as_uint(f);
  return (ushort)((u + 0x7fffu + ((u >> 16) & 1u)) >> 16);
}

__device__ inline float b2f(ushort v) {
  return __uint_as_float(((uint)v) << 16);
}

// decode one f16 from a packed 32-bit word (hi=1 -> high half)
__device__ inline float omw_decode(uint w, int hi) {
  ushort hu = hi ? (ushort)(w >> 16) : (ushort)(w & 0xffffu);
  union { ushort u; _Float16 f; } cv; cv.u = hu;
  return (float)cv.f;
}

// ---------------- fold: projW1T[n][d] = sum_k proj[d][c*64+k] * W1[c][k][i]
__global__ __launch_bounds__(256) void fold_w1_kernel(
    const float* __restrict__ proj, const float* __restrict__ W1,
    ushort* __restrict__ projW1T) {
  __shared__ float wl[64];
  const int n = blockIdx.x;           // 0..511
  const int c = n >> 6, i = n & 63;
  const int tid = threadIdx.x;
  if (tid < 64) wl[tid] = W1[c * 4096 + tid * 64 + i];
  __syncthreads();
  const float* pr = proj + (size_t)tid * 512 + c * 64;  // row d = tid
  float acc = 0.f;
#pragma unroll
  for (int k = 0; k < 64; ++k) acc += pr[k] * wl[k];
  projW1T[(size_t)n * 256 + tid] = f2bf(acc);
}

// ---------------- W2T[c][n][k] = W2[c][k][n], bf16 (B-operand layout) --------
__global__ __launch_bounds__(256) void w2t_kernel(const float* __restrict__ W2,
                                                  ushort* __restrict__ W2T) {
  int c = blockIdx.x;
  for (int idx = threadIdx.x; idx < 4096; idx += 256) {
    int nn = idx >> 6, k = idx & 63;
    W2T[(size_t)c * 4096 + idx] = f2bf(W2[(size_t)c * 4096 + k * 64 + nn]);
  }
}

// ---------------- MFMA GEMM: g1 = x @ projW1, output CHANNEL-MAJOR [C][N][64]
__global__ __launch_bounds__(256) void gemm_proj_kernel(
    const float* __restrict__ x, const ushort* __restrict__ BT,
    ushort* __restrict__ gout) {
  __shared__ ushort As[128 * 40];  // 10 KB
  __shared__ ushort Bs[128 * 40];  // 10 KB
  const int tid = threadIdx.x;
  const int lane = tid & 63, wv = tid >> 6;
  const int wm = wv >> 1, wn = wv & 1;
  const int lr = lane & 15, kg = lane >> 4;
  const int row0 = blockIdx.x * 128;
  const int col0 = blockIdx.y * 128;

  f32x4 acc[4][4];
#pragma unroll
  for (int i = 0; i < 4; ++i)
#pragma unroll
    for (int j = 0; j < 4; ++j) acc[i][j] = (f32x4){0.f, 0.f, 0.f, 0.f};

  for (int kk = 0; kk < 8; ++kk) {
    __syncthreads();
#pragma unroll
    for (int i = 0; i < 4; ++i) {
      int idx = tid + i * 256;
      int row = idx >> 3, quad = idx & 7;
      int rg = row0 + row;
      rg = rg < NN ? rg : NN - 1;
      float4 v = *(const float4*)(x + (size_t)rg * 256 + kk * 32 + quad * 4);
      ushort4 o = {f2bf(v.x), f2bf(v.y), f2bf(v.z), f2bf(v.w)};
      *(ushort4*)(As + row * 40 + quad * 4) = o;
    }
#pragma unroll
    for (int i = 0; i < 2; ++i) {
      int idx = tid + i * 256;
      int n = idx >> 2, quad = idx & 3;
      uint4 v = *(const uint4*)(BT + (size_t)(col0 + n) * 256 + kk * 32 + quad * 8);
      *(uint4*)(Bs + n * 40 + quad * 8) = v;
    }
    __syncthreads();
    bf16x8 a[4], b[4];
#pragma unroll
    for (int i = 0; i < 4; ++i)
      a[i] = *(const bf16x8*)(As + (wm * 64 + i * 16 + lr) * 40 + kg * 8);
#pragma unroll
    for (int j = 0; j < 4; ++j)
      b[j] = *(const bf16x8*)(Bs + (wn * 64 + j * 16 + lr) * 40 + kg * 8);
#pragma unroll
    for (int i = 0; i < 4; ++i)
#pragma unroll
      for (int j = 0; j < 4; ++j)
        acc[i][j] = __builtin_amdgcn_mfma_f32_16x16x32_bf16(a[i], b[j], acc[i][j], 0, 0, 0);
  }

  const int orow = kg * 4;
  const int ocol = lane & 15;
#pragma unroll
  for (int i = 0; i < 4; ++i) {
    int rg0 = row0 + wm * 64 + i * 16 + orow;
#pragma unroll
    for (int q = 0; q < 4; ++q) {
      int rg = rg0 + q;
      if (rg < NN) {
#pragma unroll
        for (int j = 0; j < 4; ++j) {
          int cc = col0 + wn * 64 + j * 16 + ocol;   // global column 0..511
          int ch = cc >> 6, ii = cc & 63;
          gout[((size_t)ch * NN + rg) * 64 + ii] = f2bf(acc[i][j][q]);
        }
      }
    }
  }
}

// ---------------- bmm: g2[c][n][64] = h1[c][n][64] @ W2[c]  (bf16 MFMA) ------
// channel-major in AND out.
__global__ __launch_bounds__(256) void bmm_g_kernel(
    const ushort* __restrict__ h, const ushort* __restrict__ WT,
    ushort* __restrict__ g) {
  __shared__ ushort As[128 * 72];   // 18 KB
  __shared__ ushort Bs[64 * 72];    // 9 KB
  __shared__ float Cs[4][32 * 68];  // 34.8 KB
  const int tid = threadIdx.x, lane = tid & 63, wv = tid >> 6;
  const int lr = lane & 15, kg = lane >> 4;
  const int n0 = blockIdx.x * 128;
  const int c = blockIdx.y;
  const ushort* hc = h + (size_t)c * NN * 64;
  ushort* gc = g + (size_t)c * NN * 64;

#pragma unroll
  for (int i = 0; i < 4; ++i) {
    int idx = tid + i * 256;
    int row = idx >> 3, q = idx & 7;
    int rg = n0 + row;
    rg = rg < NN ? rg : NN - 1;
    *(uint4*)(As + row * 72 + q * 8) = *(const uint4*)(hc + (size_t)rg * 64 + q * 8);
  }
#pragma unroll
  for (int i = 0; i < 2; ++i) {
    int idx = tid + i * 256;
    int row = idx >> 3, q = idx & 7;
    *(uint4*)(Bs + row * 72 + q * 8) =
        *(const uint4*)(WT + (size_t)c * 4096 + row * 64 + q * 8);
  }
  __syncthreads();

  f32x4 acc[2][4];
#pragma unroll
  for (int m = 0; m < 2; ++m)
#pragma unroll
    for (int j = 0; j < 4; ++j) acc[m][j] = (f32x4){0.f, 0.f, 0.f, 0.f};

#pragma unroll
  for (int ks = 0; ks < 2; ++ks) {
    bf16x8 a[2], b[4];
#pragma unroll
    for (int m = 0; m < 2; ++m)
      a[m] = *(const bf16x8*)(As + (wv * 32 + m * 16 + lr) * 72 + ks * 32 + kg * 8);
#pragma unroll
    for (int j = 0; j < 4; ++j)
      b[j] = *(const bf16x8*)(Bs + (j * 16 + lr) * 72 + ks * 32 + kg * 8);
#pragma unroll
    for (int m = 0; m < 2; ++m)
#pragma unroll
      for (int j = 0; j < 4; ++j)
        acc[m][j] = __builtin_amdgcn_mfma_f32_16x16x32_bf16(a[m], b[j], acc[m][j], 0, 0, 0);
  }

  float* cs = &Cs[wv][0];
#pragma unroll
  for (int m = 0; m < 2; ++m)
#pragma unroll
    for (int j = 0; j < 4; ++j)
#pragma unroll
      for (int q = 0; q < 4; ++q)
        cs[(m * 16 + kg * 4 + q) * 68 + j * 16 + lr] = acc[m][j][q];
  __syncthreads();

  const int row = lane & 31, half = lane >> 5;
  const int rg = n0 + wv * 32 + row;
  if (rg < NN) {
    const float* rp = cs + row * 68 + half * 32;
    ushort ob[32];
#pragma unroll
    for (int t = 0; t < 32; ++t) ob[t] = f2bf(rp[t]);
    ushort* op = gc + (size_t)rg * 64 + half * 32;
#pragma unroll
    for (int t = 0; t < 4; ++t)
      *(uint4*)(op + t * 8) = *(uint4*)(ob + t * 8);
  }
}

// ---------------- CSR build: histogram -> hierarchical scan -> fill ----------
__global__ void hist_kernel(const int* __restrict__ dst, int* __restrict__ cnt) {
  int e = blockIdx.x * 256 + threadIdx.x;
  if (e < NE) atomicAdd(&cnt[dst[e]], 1);
}

// per-1024-chunk totals
__global__ __launch_bounds__(1024) void scan1_kernel(const int* __restrict__ cnt,
                                                     int* __restrict__ blocksum) {
  __shared__ int ws[16];
  int tid = threadIdx.x, t = blockIdx.x * 1024 + tid;
  int v = (t < NN) ? cnt[t] : 0;
#pragma unroll
  for (int off = 32; off; off >>= 1) v += __shfl_xor(v, off);
  if ((tid & 63) == 0) ws[tid >> 6] = v;
  __syncthreads();
  if (tid < 16) {
    int s = ws[tid];
#pragma unroll
    for (int off = 8; off; off >>= 1) s += __shfl_xor(s, off, 16);
    if (tid == 0) blocksum[blockIdx.x] = s;
  }
}

// single wave scans the 49 block sums (exclusive); writes total to rowptr[NN]
__global__ __launch_bounds__(64) void scan2_kernel(int* __restrict__ blocksum,
                                                   int* __restrict__ rowptr) {
  int tid = threadIdx.x;
  int v = (tid < SCAN_BLOCKS) ? blocksum[tid] : 0;
  int orig = v;
#pragma unroll
  for (int off = 1; off < 64; off <<= 1) {
    int u = __shfl_up(v, off);
    if (tid >= off) v += u;
  }
  if (tid < SCAN_BLOCKS) blocksum[tid] = v - orig;  // exclusive
  if (tid == 63) rowptr[NN] = v;                    // total (=NE)
}

// full per-chunk exclusive scan + chunk offset -> rowptr & cursor
__global__ __launch_bounds__(1024) void scan3_kernel(const int* __restrict__ blocksum,
                                                     int* __restrict__ cntcur,
                                                     int* __restrict__ rowptr) {
  __shared__ int ws[16];
  int tid = threadIdx.x, lane = tid & 63, wv = tid >> 6;
  int t = blockIdx.x * 1024 + tid;
  int orig = (t < NN) ? cntcur[t] : 0;
  int v = orig;
#pragma unroll
  for (int off = 1; off < 64; off <<= 1) {
    int u = __shfl_up(v, off);
    if (lane >= off) v += u;
  }
  if (lane == 63) ws[wv] = v;
  __syncthreads();
  if (tid < 16) {
    int s = ws[tid];
#pragma unroll
    for (int off = 1; off < 16; off <<= 1) {
      int u = __shfl_up(s, off, 16);
      if (tid >= off) s += u;
    }
    ws[tid] = s;
  }
  __syncthreads();
  if (t < NN) {
    int excl = blocksum[blockIdx.x] + (wv ? ws[wv - 1] : 0) + (v - orig);
    rowptr[t] = excl;
    cntcur[t] = excl;
  }
}

// fill: CSR payload = src node + omega row packed f16x8
__global__ void fill_kernel(const int* __restrict__ dst, const int* __restrict__ src,
                            const float* __restrict__ omega, int* __restrict__ cursor,
                            int* __restrict__ esrc, uint4* __restrict__ eom) {
  int e = blockIdx.x * 256 + threadIdx.x;
  if (e < NE) {
    int d = dst[e];
    int pos = atomicAdd(&cursor[d], 1);
    esrc[pos] = src[e];
    const float4* om4 = (const float4*)(omega + (size_t)e * 8);
    float4 o0 = om4[0], o1 = om4[1];
    union { _Float16 f[8]; uint4 v; } pk;
    pk.f[0] = (_Float16)o0.x; pk.f[1] = (_Float16)o0.y;
    pk.f[2] = (_Float16)o0.z; pk.f[3] = (_Float16)o0.w;
    pk.f[4] = (_Float16)o1.x; pk.f[5] = (_Float16)o1.y;
    pk.f[6] = (_Float16)o1.z; pk.f[7] = (_Float16)o1.w;
    eom[pos] = pk.v;
  }
}

// ---------------- conv + LN (+ReLU), CHANNEL-SPLIT gather --------------------
// Block handles 4 nodes x ONE channel; c = blockIdx.x & 7 so that the
// (empirically round-robin) workgroup->XCD mapping pins channel k to XCD k,
// whose 4 MB L2 then caches (most of) that channel's 6.4 MB table.
// g is channel-major [C][NN][64]; wave gathers 128B rows (1 bf16/lane).
template <bool RELU, bool BF16OUT>
__global__ __launch_bounds__(256) void conv_ln_kernel(
    const ushort* __restrict__ g, const int* __restrict__ esrc,
    const uint* __restrict__ eomw, const int* __restrict__ rowptr,
    const float* __restrict__ gamma, const float* __restrict__ beta,
    void* __restrict__ outv) {
  const int bid = blockIdx.x;
  const int c = bid & 7;
  const int n = (bid >> 3) * 4 + (threadIdx.x >> 6);
  if (n >= NN) return;
  const int lane = threadIdx.x & 63;
  const int hi = c & 1;             // which half of the omega word
  const int cw = c >> 1;            // omega word index within the edge's 16B
  int start = rowptr[n], end = rowptr[n + 1];
  const ushort* gc = g + (size_t)c * NN * 64;
  float acc = 0.f;

  int idx = start;
  // 8x unroll: 8 independent 128B gathers in flight per wave
  for (; idx + 7 < end; idx += 8) {
    int s0 = esrc[idx + 0], s1 = esrc[idx + 1], s2 = esrc[idx + 2], s3 = esrc[idx + 3];
    int s4 = esrc[idx + 4], s5 = esrc[idx + 5], s6 = esrc[idx + 6], s7 = esrc[idx + 7];
    ushort v0 = gc[(size_t)s0 * 64 + lane];
    ushort v1 = gc[(size_t)s1 * 64 + lane];
    ushort v2 = gc[(size_t)s2 * 64 + lane];
    ushort v3 = gc[(size_t)s3 * 64 + lane];
    ushort v4 = gc[(size_t)s4 * 64 + lane];
    ushort v5 = gc[(size_t)s5 * 64 + lane];
    ushort v6 = gc[(size_t)s6 * 64 + lane];
    ushort v7 = gc[(size_t)s7 * 64 + lane];
    float w0 = omw_decode(eomw[(idx + 0) * 4 + cw], hi);
    float w1 = omw_decode(eomw[(idx + 1) * 4 + cw], hi);
    float w2 = omw_decode(eomw[(idx + 2) * 4 + cw], hi);
    float w3 = omw_decode(eomw[(idx + 3) * 4 + cw], hi);
    float w4 = omw_decode(eomw[(idx + 4) * 4 + cw], hi);
    float w5 = omw_decode(eomw[(idx + 5) * 4 + cw], hi);
    float w6 = omw_decode(eomw[(idx + 6) * 4 + cw], hi);
    float w7 = omw_decode(eomw[(idx + 7) * 4 + cw], hi);
    acc += w0 * b2f(v0); acc += w1 * b2f(v1);
    acc += w2 * b2f(v2); acc += w3 * b2f(v3);
    acc += w4 * b2f(v4); acc += w5 * b2f(v5);
    acc += w6 * b2f(v6); acc += w7 * b2f(v7);
  }
  for (; idx + 3 < end; idx += 4) {
    int s0 = esrc[idx + 0], s1 = esrc[idx + 1], s2 = esrc[idx + 2], s3 = esrc[idx + 3];
    ushort v0 = gc[(size_t)s0 * 64 + lane];
    ushort v1 = gc[(size_t)s1 * 64 + lane];
    ushort v2 = gc[(size_t)s2 * 64 + lane];
    ushort v3 = gc[(size_t)s3 * 64 + lane];
    float w0 = omw_decode(eomw[(idx + 0) * 4 + cw], hi);
    float w1 = omw_decode(eomw[(idx + 1) * 4 + cw], hi);
    float w2 = omw_decode(eomw[(idx + 2) * 4 + cw], hi);
    float w3 = omw_decode(eomw[(idx + 3) * 4 + cw], hi);
    acc += w0 * b2f(v0); acc += w1 * b2f(v1);
    acc += w2 * b2f(v2); acc += w3 * b2f(v3);
  }
  for (; idx < end; ++idx) {
    ushort v = gc[(size_t)esrc[idx] * 64 + lane];
    acc += omw_decode(eomw[idx * 4 + cw], hi) * b2f(v);
  }

  // LayerNorm over the 64 lanes (the H axis of channel c)
  float s = acc;
#pragma unroll
  for (int off = 32; off; off >>= 1) s += __shfl_xor(s, off);
  float mu = s * (1.f / 64.f);
  float d = acc - mu;
  float v2 = d * d;
#pragma unroll
  for (int off = 32; off; off >>= 1) v2 += __shfl_xor(v2, off);
  float inv = rsqrtf(v2 * (1.f / 64.f) + LN_EPS);
  float y = d * inv * gamma[lane] + beta[lane];
  if (RELU) y = fmaxf(y, 0.f);
  if (BF16OUT) {
    ((ushort*)outv)[((size_t)c * NN + n) * 64 + lane] = f2bf(y);  // channel-major
  } else {
    ((float*)outv)[(size_t)n * 512 + c * 64 + lane] = y;          // final layout
  }
}

extern "C" void kernel_launch(void* const* d_in, const int* in_sizes, int n_in,
                              void* d_out, int out_size, void* d_ws, size_t ws_size,
                              hipStream_t stream) {
  const float* x     = (const float*)d_in[0];
  const int*   edge  = (const int*)d_in[1];   // [2,E]: src then dst
  const float* omega = (const float*)d_in[2]; // [E,8]
  const float* proj  = (const float*)d_in[3]; // [256,512]
  const float* W1    = (const float*)d_in[4]; // [8,64,64]
  const float* W2    = (const float*)d_in[5];
  const float* gamma = (const float*)d_in[6];
  const float* beta  = (const float*)d_in[7];
  const int* src = edge;
  const int* dst = edge + NE;

  // ws layout (16B-aligned): hbf | eom | esrc | rowptr | cntcur | blocksum | projW1T | W2T
  char* p = (char*)d_ws;
  ushort* hbf    = (ushort*)p;              p += (size_t)NN * CHW * 2;   // 51.2 MB
  uint4*  eom    = (uint4*)p;               p += (size_t)NE * 16;        // 12.8 MB
  int*    esrc   = (int*)p;                 p += (size_t)NE * 4;         // 3.2 MB
  int*    rowptr = (int*)p;                 p += (size_t)(NN + 16) * 4;
  int*    cntcur = (int*)p;                 p += (size_t)(NN + 16) * 4;
  int*    blocksum=(int*)p;                 p += (size_t)64 * 4;
  ushort* projW1T= (ushort*)p;              p += (size_t)512 * 256 * 2;
  ushort* W2T    = (ushort*)p;

  ushort* h1 = (ushort*)d_out;  // h1 bf16 (channel-major) in d_out's first half
                                // (dead before the final f32 write overwrites it)

  // ---- CSR build ----
  hipMemsetAsync(cntcur, 0, NN * sizeof(int), stream);
  hist_kernel<<<(NE + 255) / 256, 256, 0, stream>>>(dst, cntcur);
  scan1_kernel<<<SCAN_BLOCKS, 1024, 0, stream>>>(cntcur, blocksum);
  scan2_kernel<<<1, 64, 0, stream>>>(blocksum, rowptr);
  scan3_kernel<<<SCAN_BLOCKS, 1024, 0, stream>>>(blocksum, cntcur, rowptr);
  fill_kernel<<<(NE + 255) / 256, 256, 0, stream>>>(dst, src, omega, cntcur, esrc, eom);

  // ---- parameter prep ----
  fold_w1_kernel<<<512, 256, 0, stream>>>(proj, W1, projW1T);
  w2t_kernel<<<8, 256, 0, stream>>>(W2, W2T);

  const int conv_blocks = ((NN + 3) / 4) * 8;

  // ---- layer 0: g1 = x @ projW1 (channel-major) -> h1 = ReLU(LN(gather)) ----
  gemm_proj_kernel<<<dim3((NN + 127) / 128, 4), 256, 0, stream>>>(x, projW1T, hbf);
  conv_ln_kernel<true, true><<<conv_blocks, 256, 0, stream>>>(
      hbf, esrc, (const uint*)eom, rowptr, gamma, beta, h1);

  // ---- layer 1: g2 = h1 @ W2 (channel-major) -> out = LN(gather(g2)) ----
  bmm_g_kernel<<<dim3((NN + 127) / 128, CC), 256, 0, stream>>>(h1, W2T, hbf);
  conv_ln_kernel<false, false><<<conv_blocks, 256, 0, stream>>>(
      hbf, esrc, (const uint*)eom, rowptr, gamma, beta, d_out);
}

// Round 10
// 515.450 us; speedup vs baseline: 1.1738x; 1.1738x over previous
//
#include <hip/hip_runtime.h>

#define NN 50000
#define NE 800000
#define DD 256
#define CC 8
#define HH 64
#define CHW 512   // C*H
#define LN_EPS 1e-5f
#define SCAN_BLOCKS ((NN + 1023) / 1024)  // 49

typedef __attribute__((ext_vector_type(8))) __bf16 bf16x8;
typedef __attribute__((ext_vector_type(4))) float f32x4;

// round-to-nearest-even f32 -> bf16 (values are finite here)
__device__ inline ushort f2bf(float f) {
  uint u = __float_as_uint(f);
  return (ushort)((u + 0x7fffu + ((u >> 16) & 1u)) >> 16);
}

// decode one f16 from a packed 32-bit word (hi=1 -> high half)
__device__ inline float omw_decode(uint w, int hi) {
  ushort hu = hi ? (ushort)(w >> 16) : (ushort)(w & 0xffffu);
  union { ushort u; _Float16 f; } cv; cv.u = hu;
  return (float)cv.f;
}

// accumulate 8 bf16 lanes of hv (packed in uint4) scaled by wt into acc[8]
__device__ inline void acc8(float* acc, uint4 hv, float wt) {
  acc[0] += wt * __uint_as_float(hv.x << 16);
  acc[1] += wt * __uint_as_float(hv.x & 0xffff0000u);
  acc[2] += wt * __uint_as_float(hv.y << 16);
  acc[3] += wt * __uint_as_float(hv.y & 0xffff0000u);
  acc[4] += wt * __uint_as_float(hv.z << 16);
  acc[5] += wt * __uint_as_float(hv.z & 0xffff0000u);
  acc[6] += wt * __uint_as_float(hv.w << 16);
  acc[7] += wt * __uint_as_float(hv.w & 0xffff0000u);
}

// ---------------- fold: projW1T[n][d] = sum_k proj[d][c*64+k] * W1[c][k][i]
__global__ __launch_bounds__(256) void fold_w1_kernel(
    const float* __restrict__ proj, const float* __restrict__ W1,
    ushort* __restrict__ projW1T) {
  __shared__ float wl[64];
  const int n = blockIdx.x;           // 0..511
  const int c = n >> 6, i = n & 63;
  const int tid = threadIdx.x;
  if (tid < 64) wl[tid] = W1[c * 4096 + tid * 64 + i];
  __syncthreads();
  const float* pr = proj + (size_t)tid * 512 + c * 64;  // row d = tid
  float acc = 0.f;
#pragma unroll
  for (int k = 0; k < 64; ++k) acc += pr[k] * wl[k];
  projW1T[(size_t)n * 256 + tid] = f2bf(acc);
}

// ---------------- W2T[c][n][k] = W2[c][k][n], bf16 (B-operand layout) --------
__global__ __launch_bounds__(256) void w2t_kernel(const float* __restrict__ W2,
                                                  ushort* __restrict__ W2T) {
  int c = blockIdx.x;
  for (int idx = threadIdx.x; idx < 4096; idx += 256) {
    int nn = idx >> 6, k = idx & 63;
    W2T[(size_t)c * 4096 + idx] = f2bf(W2[(size_t)c * 4096 + k * 64 + nn]);
  }
}

// ---------------- MFMA GEMM: g1 = x @ projW1, output CHANNEL-MAJOR [C][N][64]
__global__ __launch_bounds__(256) void gemm_proj_kernel(
    const float* __restrict__ x, const ushort* __restrict__ BT,
    ushort* __restrict__ gout) {
  __shared__ ushort As[128 * 40];  // 10 KB
  __shared__ ushort Bs[128 * 40];  // 10 KB
  const int tid = threadIdx.x;
  const int lane = tid & 63, wv = tid >> 6;
  const int wm = wv >> 1, wn = wv & 1;
  const int lr = lane & 15, kg = lane >> 4;
  const int row0 = blockIdx.x * 128;
  const int col0 = blockIdx.y * 128;

  f32x4 acc[4][4];
#pragma unroll
  for (int i = 0; i < 4; ++i)
#pragma unroll
    for (int j = 0; j < 4; ++j) acc[i][j] = (f32x4){0.f, 0.f, 0.f, 0.f};

  for (int kk = 0; kk < 8; ++kk) {
    __syncthreads();
#pragma unroll
    for (int i = 0; i < 4; ++i) {
      int idx = tid + i * 256;
      int row = idx >> 3, quad = idx & 7;
      int rg = row0 + row;
      rg = rg < NN ? rg : NN - 1;
      float4 v = *(const float4*)(x + (size_t)rg * 256 + kk * 32 + quad * 4);
      ushort4 o = {f2bf(v.x), f2bf(v.y), f2bf(v.z), f2bf(v.w)};
      *(ushort4*)(As + row * 40 + quad * 4) = o;
    }
#pragma unroll
    for (int i = 0; i < 2; ++i) {
      int idx = tid + i * 256;
      int n = idx >> 2, quad = idx & 3;
      uint4 v = *(const uint4*)(BT + (size_t)(col0 + n) * 256 + kk * 32 + quad * 8);
      *(uint4*)(Bs + n * 40 + quad * 8) = v;
    }
    __syncthreads();
    bf16x8 a[4], b[4];
#pragma unroll
    for (int i = 0; i < 4; ++i)
      a[i] = *(const bf16x8*)(As + (wm * 64 + i * 16 + lr) * 40 + kg * 8);
#pragma unroll
    for (int j = 0; j < 4; ++j)
      b[j] = *(const bf16x8*)(Bs + (wn * 64 + j * 16 + lr) * 40 + kg * 8);
#pragma unroll
    for (int i = 0; i < 4; ++i)
#pragma unroll
      for (int j = 0; j < 4; ++j)
        acc[i][j] = __builtin_amdgcn_mfma_f32_16x16x32_bf16(a[i], b[j], acc[i][j], 0, 0, 0);
  }

  const int orow = kg * 4;
  const int ocol = lane & 15;
#pragma unroll
  for (int i = 0; i < 4; ++i) {
    int rg0 = row0 + wm * 64 + i * 16 + orow;
#pragma unroll
    for (int q = 0; q < 4; ++q) {
      int rg = rg0 + q;
      if (rg < NN) {
#pragma unroll
        for (int j = 0; j < 4; ++j) {
          int cc = col0 + wn * 64 + j * 16 + ocol;   // global column 0..511
          int ch = cc >> 6, ii = cc & 63;
          gout[((size_t)ch * NN + rg) * 64 + ii] = f2bf(acc[i][j][q]);
        }
      }
    }
  }
}

// ---------------- bmm: g2[c][n][64] = h1[c][n][64] @ W2[c]  (bf16 MFMA) ------
// channel-major in AND out.
__global__ __launch_bounds__(256) void bmm_g_kernel(
    const ushort* __restrict__ h, const ushort* __restrict__ WT,
    ushort* __restrict__ g) {
  __shared__ ushort As[128 * 72];   // 18 KB
  __shared__ ushort Bs[64 * 72];    // 9 KB
  __shared__ float Cs[4][32 * 68];  // 34.8 KB
  const int tid = threadIdx.x, lane = tid & 63, wv = tid >> 6;
  const int lr = lane & 15, kg = lane >> 4;
  const int n0 = blockIdx.x * 128;
  const int c = blockIdx.y;
  const ushort* hc = h + (size_t)c * NN * 64;
  ushort* gc = g + (size_t)c * NN * 64;

#pragma unroll
  for (int i = 0; i < 4; ++i) {
    int idx = tid + i * 256;
    int row = idx >> 3, q = idx & 7;
    int rg = n0 + row;
    rg = rg < NN ? rg : NN - 1;
    *(uint4*)(As + row * 72 + q * 8) = *(const uint4*)(hc + (size_t)rg * 64 + q * 8);
  }
#pragma unroll
  for (int i = 0; i < 2; ++i) {
    int idx = tid + i * 256;
    int row = idx >> 3, q = idx & 7;
    *(uint4*)(Bs + row * 72 + q * 8) =
        *(const uint4*)(WT + (size_t)c * 4096 + row * 64 + q * 8);
  }
  __syncthreads();

  f32x4 acc[2][4];
#pragma unroll
  for (int m = 0; m < 2; ++m)
#pragma unroll
    for (int j = 0; j < 4; ++j) acc[m][j] = (f32x4){0.f, 0.f, 0.f, 0.f};

#pragma unroll
  for (int ks = 0; ks < 2; ++ks) {
    bf16x8 a[2], b[4];
#pragma unroll
    for (int m = 0; m < 2; ++m)
      a[m] = *(const bf16x8*)(As + (wv * 32 + m * 16 + lr) * 72 + ks * 32 + kg * 8);
#pragma unroll
    for (int j = 0; j < 4; ++j)
      b[j] = *(const bf16x8*)(Bs + (j * 16 + lr) * 72 + ks * 32 + kg * 8);
#pragma unroll
    for (int m = 0; m < 2; ++m)
#pragma unroll
      for (int j = 0; j < 4; ++j)
        acc[m][j] = __builtin_amdgcn_mfma_f32_16x16x32_bf16(a[m], b[j], acc[m][j], 0, 0, 0);
  }

  float* cs = &Cs[wv][0];
#pragma unroll
  for (int m = 0; m < 2; ++m)
#pragma unroll
    for (int j = 0; j < 4; ++j)
#pragma unroll
      for (int q = 0; q < 4; ++q)
        cs[(m * 16 + kg * 4 + q) * 68 + j * 16 + lr] = acc[m][j][q];
  __syncthreads();

  const int row = lane & 31, half = lane >> 5;
  const int rg = n0 + wv * 32 + row;
  if (rg < NN) {
    const float* rp = cs + row * 68 + half * 32;
    ushort ob[32];
#pragma unroll
    for (int t = 0; t < 32; ++t) ob[t] = f2bf(rp[t]);
    ushort* op = gc + (size_t)rg * 64 + half * 32;
#pragma unroll
    for (int t = 0; t < 4; ++t)
      *(uint4*)(op + t * 8) = *(uint4*)(ob + t * 8);
  }
}

// ---------------- CSR build: histogram -> hierarchical scan -> fill ----------
__global__ void hist_kernel(const int* __restrict__ dst, int* __restrict__ cnt) {
  int e = blockIdx.x * 256 + threadIdx.x;
  if (e < NE) atomicAdd(&cnt[dst[e]], 1);
}

// per-1024-chunk totals
__global__ __launch_bounds__(1024) void scan1_kernel(const int* __restrict__ cnt,
                                                     int* __restrict__ blocksum) {
  __shared__ int ws[16];
  int tid = threadIdx.x, t = blockIdx.x * 1024 + tid;
  int v = (t < NN) ? cnt[t] : 0;
#pragma unroll
  for (int off = 32; off; off >>= 1) v += __shfl_xor(v, off);
  if ((tid & 63) == 0) ws[tid >> 6] = v;
  __syncthreads();
  if (tid < 16) {
    int s = ws[tid];
#pragma unroll
    for (int off = 8; off; off >>= 1) s += __shfl_xor(s, off, 16);
    if (tid == 0) blocksum[blockIdx.x] = s;
  }
}

// single wave scans the 49 block sums (exclusive); writes total to rowptr[NN]
__global__ __launch_bounds__(64) void scan2_kernel(int* __restrict__ blocksum,
                                                   int* __restrict__ rowptr) {
  int tid = threadIdx.x;
  int v = (tid < SCAN_BLOCKS) ? blocksum[tid] : 0;
  int orig = v;
#pragma unroll
  for (int off = 1; off < 64; off <<= 1) {
    int u = __shfl_up(v, off);
    if (tid >= off) v += u;
  }
  if (tid < SCAN_BLOCKS) blocksum[tid] = v - orig;  // exclusive
  if (tid == 63) rowptr[NN] = v;                    // total (=NE)
}

// full per-chunk exclusive scan + chunk offset -> rowptr & cursor
__global__ __launch_bounds__(1024) void scan3_kernel(const int* __restrict__ blocksum,
                                                     int* __restrict__ cntcur,
                                                     int* __restrict__ rowptr) {
  __shared__ int ws[16];
  int tid = threadIdx.x, lane = tid & 63, wv = tid >> 6;
  int t = blockIdx.x * 1024 + tid;
  int orig = (t < NN) ? cntcur[t] : 0;
  int v = orig;
#pragma unroll
  for (int off = 1; off < 64; off <<= 1) {
    int u = __shfl_up(v, off);
    if (lane >= off) v += u;
  }
  if (lane == 63) ws[wv] = v;
  __syncthreads();
  if (tid < 16) {
    int s = ws[tid];
#pragma unroll
    for (int off = 1; off < 16; off <<= 1) {
      int u = __shfl_up(s, off, 16);
      if (tid >= off) s += u;
    }
    ws[tid] = s;
  }
  __syncthreads();
  if (t < NN) {
    int excl = blocksum[blockIdx.x] + (wv ? ws[wv - 1] : 0) + (v - orig);
    rowptr[t] = excl;
    cntcur[t] = excl;
  }
}

// fill: CSR payload = src node + omega row packed f16x8
__global__ void fill_kernel(const int* __restrict__ dst, const int* __restrict__ src,
                            const float* __restrict__ omega, int* __restrict__ cursor,
                            int* __restrict__ esrc, uint4* __restrict__ eom) {
  int e = blockIdx.x * 256 + threadIdx.x;
  if (e < NE) {
    int d = dst[e];
    int pos = atomicAdd(&cursor[d], 1);
    esrc[pos] = src[e];
    const float4* om4 = (const float4*)(omega + (size_t)e * 8);
    float4 o0 = om4[0], o1 = om4[1];
    union { _Float16 f[8]; uint4 v; } pk;
    pk.f[0] = (_Float16)o0.x; pk.f[1] = (_Float16)o0.y;
    pk.f[2] = (_Float16)o0.z; pk.f[3] = (_Float16)o0.w;
    pk.f[4] = (_Float16)o1.x; pk.f[5] = (_Float16)o1.y;
    pk.f[6] = (_Float16)o1.z; pk.f[7] = (_Float16)o1.w;
    eom[pos] = pk.v;
  }
}

// ---------------- conv + LN (+ReLU), channel-split, 8-edges-per-wave ---------
// Block: 4 nodes x ONE channel (c = blockIdx.x & 7 -> XCD-pinned table slice).
// Wave iteration: lane (grp=lane>>3, sub=lane&7) reads 16B of edge (idx+grp)'s
// 128B channel-row -> 1 KB gathered per iteration (8 edges), like R7, but
// within the 6.4 MB per-channel table that one XCD's L2 can hold.
template <bool RELU, bool BF16OUT>
__global__ __launch_bounds__(256) void conv_ln_kernel(
    const ushort* __restrict__ g, const int* __restrict__ esrc,
    const uint* __restrict__ eomw, const int* __restrict__ rowptr,
    const float* __restrict__ gamma, const float* __restrict__ beta,
    void* __restrict__ outv) {
  const int bid = blockIdx.x;
  const int c = bid & 7;
  const int n = (bid >> 3) * 4 + (threadIdx.x >> 6);
  if (n >= NN) return;
  const int lane = threadIdx.x & 63;
  const int grp = lane >> 3;        // which edge of the 8-edge batch
  const int sub = lane & 7;         // which 16B of the 128B row
  const int i0 = sub * 8;           // H-offset of this lane's 8 elements
  const int hi = c & 1;
  const int cw = c >> 1;
  const int start = rowptr[n], end = rowptr[n + 1];
  const uint4* gc4 = (const uint4*)(g + (size_t)c * NN * 64);  // 8 uint4 / row
  float acc[8] = {0.f, 0.f, 0.f, 0.f, 0.f, 0.f, 0.f, 0.f};

  int idx = start;
  // two 8-edge batches in flight (covers the average degree-16 node fully)
  for (; idx + 8 < end; idx += 16) {
    int e0 = idx + grp;
    int e1 = idx + 8 + grp;
    bool p1 = e1 < end;
    int e1c = p1 ? e1 : end - 1;
    int s0 = esrc[e0];
    int s1 = esrc[e1c];
    uint4 h0 = gc4[(size_t)s0 * 8 + sub];
    uint4 h1 = gc4[(size_t)s1 * 8 + sub];
    float w0 = omw_decode(eomw[e0 * 4 + cw], hi);
    float w1 = p1 ? omw_decode(eomw[e1c * 4 + cw], hi) : 0.f;
    acc8(acc, h0, w0);
    acc8(acc, h1, w1);
  }
  if (idx < end) {
    int e0 = idx + grp;
    bool p0 = e0 < end;
    int e0c = p0 ? e0 : end - 1;
    int s0 = esrc[e0c];
    uint4 h0 = gc4[(size_t)s0 * 8 + sub];
    float w0 = p0 ? omw_decode(eomw[e0c * 4 + cw], hi) : 0.f;
    acc8(acc, h0, w0);
  }

  // reduce across the 8 edge-groups (lanes differing in bits 3..5)
#pragma unroll
  for (int j = 0; j < 8; ++j) {
    acc[j] += __shfl_xor(acc[j], 8);
    acc[j] += __shfl_xor(acc[j], 16);
    acc[j] += __shfl_xor(acc[j], 32);
  }

  // LayerNorm over the 64 H-values (8 sub-lanes x 8 each)
  float s8 = ((acc[0] + acc[1]) + (acc[2] + acc[3])) +
             ((acc[4] + acc[5]) + (acc[6] + acc[7]));
  s8 += __shfl_xor(s8, 1);
  s8 += __shfl_xor(s8, 2);
  s8 += __shfl_xor(s8, 4);
  float mu = s8 * (1.f / 64.f);
  float d[8];
  float v = 0.f;
#pragma unroll
  for (int j = 0; j < 8; ++j) {
    d[j] = acc[j] - mu;
    v += d[j] * d[j];
  }
  v += __shfl_xor(v, 1);
  v += __shfl_xor(v, 2);
  v += __shfl_xor(v, 4);
  float inv = rsqrtf(v * (1.f / 64.f) + LN_EPS);

  if (grp == 0) {  // groups hold identical values now; group 0 writes 128B
    float4 g0 = *(const float4*)(gamma + i0);
    float4 g1 = *(const float4*)(gamma + i0 + 4);
    float4 b0 = *(const float4*)(beta + i0);
    float4 b1 = *(const float4*)(beta + i0 + 4);
    float gg[8] = {g0.x, g0.y, g0.z, g0.w, g1.x, g1.y, g1.z, g1.w};
    float bb[8] = {b0.x, b0.y, b0.z, b0.w, b1.x, b1.y, b1.z, b1.w};
    float y[8];
#pragma unroll
    for (int j = 0; j < 8; ++j) {
      float t = d[j] * inv * gg[j] + bb[j];
      y[j] = RELU ? fmaxf(t, 0.f) : t;
    }
    if (BF16OUT) {
      ushort o[8];
#pragma unroll
      for (int j = 0; j < 8; ++j) o[j] = f2bf(y[j]);
      *(uint4*)((ushort*)outv + ((size_t)c * NN + n) * 64 + i0) = *(uint4*)o;
    } else {
      float* op = (float*)outv + (size_t)n * 512 + c * 64 + i0;
      *(float4*)op = make_float4(y[0], y[1], y[2], y[3]);
      *(float4*)(op + 4) = make_float4(y[4], y[5], y[6], y[7]);
    }
  }
}

extern "C" void kernel_launch(void* const* d_in, const int* in_sizes, int n_in,
                              void* d_out, int out_size, void* d_ws, size_t ws_size,
                              hipStream_t stream) {
  const float* x     = (const float*)d_in[0];
  const int*   edge  = (const int*)d_in[1];   // [2,E]: src then dst
  const float* omega = (const float*)d_in[2]; // [E,8]
  const float* proj  = (const float*)d_in[3]; // [256,512]
  const float* W1    = (const float*)d_in[4]; // [8,64,64]
  const float* W2    = (const float*)d_in[5];
  const float* gamma = (const float*)d_in[6];
  const float* beta  = (const float*)d_in[7];
  const int* src = edge;
  const int* dst = edge + NE;

  // ws layout (16B-aligned): hbf | eom | esrc | rowptr | cntcur | blocksum | projW1T | W2T
  char* p = (char*)d_ws;
  ushort* hbf    = (ushort*)p;              p += (size_t)NN * CHW * 2;   // 51.2 MB
  uint4*  eom    = (uint4*)p;               p += (size_t)NE * 16;        // 12.8 MB
  int*    esrc   = (int*)p;                 p += (size_t)NE * 4;         // 3.2 MB
  int*    rowptr = (int*)p;                 p += (size_t)(NN + 16) * 4;
  int*    cntcur = (int*)p;                 p += (size_t)(NN + 16) * 4;
  int*    blocksum=(int*)p;                 p += (size_t)64 * 4;
  ushort* projW1T= (ushort*)p;              p += (size_t)512 * 256 * 2;
  ushort* W2T    = (ushort*)p;

  ushort* h1 = (ushort*)d_out;  // h1 bf16 (channel-major) in d_out's first half
                                // (dead before the final f32 write overwrites it)

  // ---- CSR build ----
  hipMemsetAsync(cntcur, 0, NN * sizeof(int), stream);
  hist_kernel<<<(NE + 255) / 256, 256, 0, stream>>>(dst, cntcur);
  scan1_kernel<<<SCAN_BLOCKS, 1024, 0, stream>>>(cntcur, blocksum);
  scan2_kernel<<<1, 64, 0, stream>>>(blocksum, rowptr);
  scan3_kernel<<<SCAN_BLOCKS, 1024, 0, stream>>>(blocksum, cntcur, rowptr);
  fill_kernel<<<(NE + 255) / 256, 256, 0, stream>>>(dst, src, omega, cntcur, esrc, eom);

  // ---- parameter prep ----
  fold_w1_kernel<<<512, 256, 0, stream>>>(proj, W1, projW1T);
  w2t_kernel<<<8, 256, 0, stream>>>(W2, W2T);

  const int conv_blocks = ((NN + 3) / 4) * 8;

  // ---- layer 0: g1 = x @ projW1 (channel-major) -> h1 = ReLU(LN(gather)) ----
  gemm_proj_kernel<<<dim3((NN + 127) / 128, 4), 256, 0, stream>>>(x, projW1T, hbf);
  conv_ln_kernel<true, true><<<conv_blocks, 256, 0, stream>>>(
      hbf, esrc, (const uint*)eom, rowptr, gamma, beta, h1);

  // ---- layer 1: g2 = h1 @ W2 (channel-major) -> out = LN(gather(g2)) ----
  bmm_g_kernel<<<dim3((NN + 127) / 128, CC), 256, 0, stream>>>(h1, W2T, hbf);
  conv_ln_kernel<false, false><<<conv_blocks, 256, 0, stream>>>(
      hbf, esrc, (const uint*)eom, rowptr, gamma, beta, d_out);
}

// Round 11
// 410.971 us; speedup vs baseline: 1.4722x; 1.2542x over previous
//
#include <hip/hip_runtime.h>

#define NN 50000
#define NE 800000
#define DD 256
#define CC 8
#define HH 64
#define CHW 512   // C*H
#define LN_EPS 1e-5f
#define SCAN_BLOCKS ((NN + 1023) / 1024)  // 49

typedef __attribute__((ext_vector_type(8))) __bf16 bf16x8;
typedef __attribute__((ext_vector_type(4))) float f32x4;

// round-to-nearest-even f32 -> bf16 (values are finite here)
__device__ inline ushort f2bf(float f) {
  uint u = __float_as_uint(f);
  return (ushort)((u + 0x7fffu + ((u >> 16) & 1u)) >> 16);
}

// decode one f16 from a packed 32-bit word (hi=1 -> high half)
__device__ inline float omw_decode(uint w, int hi) {
  ushort hu = hi ? (ushort)(w >> 16) : (ushort)(w & 0xffffu);
  union { ushort u; _Float16 f; } cv; cv.u = hu;
  return (float)cv.f;
}

// accumulate 8 bf16 lanes of hv (packed in uint4) scaled by wt into acc[8]
__device__ inline void acc8(float* acc, uint4 hv, float wt) {
  acc[0] += wt * __uint_as_float(hv.x << 16);
  acc[1] += wt * __uint_as_float(hv.x & 0xffff0000u);
  acc[2] += wt * __uint_as_float(hv.y << 16);
  acc[3] += wt * __uint_as_float(hv.y & 0xffff0000u);
  acc[4] += wt * __uint_as_float(hv.z << 16);
  acc[5] += wt * __uint_as_float(hv.z & 0xffff0000u);
  acc[6] += wt * __uint_as_float(hv.w << 16);
  acc[7] += wt * __uint_as_float(hv.w & 0xffff0000u);
}

// ---------------- fold: projW1T[n][d] = sum_k proj[d][c*64+k] * W1[c][k][i]
__global__ __launch_bounds__(256) void fold_w1_kernel(
    const float* __restrict__ proj, const float* __restrict__ W1,
    ushort* __restrict__ projW1T) {
  __shared__ float wl[64];
  const int n = blockIdx.x;           // 0..511
  const int c = n >> 6, i = n & 63;
  const int tid = threadIdx.x;
  if (tid < 64) wl[tid] = W1[c * 4096 + tid * 64 + i];
  __syncthreads();
  const float* pr = proj + (size_t)tid * 512 + c * 64;  // row d = tid
  float acc = 0.f;
#pragma unroll
  for (int k = 0; k < 64; ++k) acc += pr[k] * wl[k];
  projW1T[(size_t)n * 256 + tid] = f2bf(acc);
}

// ---------------- W2T[c][n][k] = W2[c][k][n], bf16 (B-operand layout) --------
__global__ __launch_bounds__(256) void w2t_kernel(const float* __restrict__ W2,
                                                  ushort* __restrict__ W2T) {
  int c = blockIdx.x;
  for (int idx = threadIdx.x; idx < 4096; idx += 256) {
    int nn = idx >> 6, k = idx & 63;
    W2T[(size_t)c * 4096 + idx] = f2bf(W2[(size_t)c * 4096 + k * 64 + nn]);
  }
}

// ---------------- MFMA GEMM: g1[N,512](bf16) = x[N,256] @ projW1 -------------
__global__ __launch_bounds__(256) void gemm_proj_kernel(
    const float* __restrict__ x, const ushort* __restrict__ BT,
    ushort* __restrict__ gout) {
  __shared__ ushort As[128 * 40];  // 10 KB
  __shared__ ushort Bs[128 * 40];  // 10 KB
  const int tid = threadIdx.x;
  const int lane = tid & 63, wv = tid >> 6;
  const int wm = wv >> 1, wn = wv & 1;
  const int lr = lane & 15, kg = lane >> 4;
  const int row0 = blockIdx.x * 128;
  const int col0 = blockIdx.y * 128;

  f32x4 acc[4][4];
#pragma unroll
  for (int i = 0; i < 4; ++i)
#pragma unroll
    for (int j = 0; j < 4; ++j) acc[i][j] = (f32x4){0.f, 0.f, 0.f, 0.f};

  for (int kk = 0; kk < 8; ++kk) {
    __syncthreads();
#pragma unroll
    for (int i = 0; i < 4; ++i) {
      int idx = tid + i * 256;
      int row = idx >> 3, quad = idx & 7;
      int rg = row0 + row;
      rg = rg < NN ? rg : NN - 1;
      float4 v = *(const float4*)(x + (size_t)rg * 256 + kk * 32 + quad * 4);
      ushort4 o = {f2bf(v.x), f2bf(v.y), f2bf(v.z), f2bf(v.w)};
      *(ushort4*)(As + row * 40 + quad * 4) = o;
    }
#pragma unroll
    for (int i = 0; i < 2; ++i) {
      int idx = tid + i * 256;
      int n = idx >> 2, quad = idx & 3;
      uint4 v = *(const uint4*)(BT + (size_t)(col0 + n) * 256 + kk * 32 + quad * 8);
      *(uint4*)(Bs + n * 40 + quad * 8) = v;
    }
    __syncthreads();
    bf16x8 a[4], b[4];
#pragma unroll
    for (int i = 0; i < 4; ++i)
      a[i] = *(const bf16x8*)(As + (wm * 64 + i * 16 + lr) * 40 + kg * 8);
#pragma unroll
    for (int j = 0; j < 4; ++j)
      b[j] = *(const bf16x8*)(Bs + (wn * 64 + j * 16 + lr) * 40 + kg * 8);
#pragma unroll
    for (int i = 0; i < 4; ++i)
#pragma unroll
      for (int j = 0; j < 4; ++j)
        acc[i][j] = __builtin_amdgcn_mfma_f32_16x16x32_bf16(a[i], b[j], acc[i][j], 0, 0, 0);
  }

  const int orow = kg * 4;
  const int ocol = lane & 15;
#pragma unroll
  for (int i = 0; i < 4; ++i) {
    int rg0 = row0 + wm * 64 + i * 16 + orow;
#pragma unroll
    for (int q = 0; q < 4; ++q) {
      int rg = rg0 + q;
      if (rg < NN) {
#pragma unroll
        for (int j = 0; j < 4; ++j) {
          gout[(size_t)rg * 512 + col0 + wn * 64 + j * 16 + ocol] = f2bf(acc[i][j][q]);
        }
      }
    }
  }
}

// ---------------- bmm: g2[n, c*64..] = h1[n, c*64..] @ W2[c]  (bf16 MFMA) ----
__global__ __launch_bounds__(256) void bmm_g_kernel(
    const ushort* __restrict__ h, const ushort* __restrict__ WT,
    ushort* __restrict__ g) {
  __shared__ ushort As[128 * 72];   // 18 KB
  __shared__ ushort Bs[64 * 72];    // 9 KB
  __shared__ float Cs[4][32 * 68];  // 34.8 KB
  const int tid = threadIdx.x, lane = tid & 63, wv = tid >> 6;
  const int lr = lane & 15, kg = lane >> 4;
  const int n0 = blockIdx.x * 128;
  const int c = blockIdx.y;

#pragma unroll
  for (int i = 0; i < 4; ++i) {
    int idx = tid + i * 256;
    int row = idx >> 3, q = idx & 7;
    int rg = n0 + row;
    rg = rg < NN ? rg : NN - 1;
    *(uint4*)(As + row * 72 + q * 8) =
        *(const uint4*)(h + (size_t)rg * 512 + c * 64 + q * 8);
  }
#pragma unroll
  for (int i = 0; i < 2; ++i) {
    int idx = tid + i * 256;
    int row = idx >> 3, q = idx & 7;
    *(uint4*)(Bs + row * 72 + q * 8) =
        *(const uint4*)(WT + (size_t)c * 4096 + row * 64 + q * 8);
  }
  __syncthreads();

  f32x4 acc[2][4];
#pragma unroll
  for (int m = 0; m < 2; ++m)
#pragma unroll
    for (int j = 0; j < 4; ++j) acc[m][j] = (f32x4){0.f, 0.f, 0.f, 0.f};

#pragma unroll
  for (int ks = 0; ks < 2; ++ks) {
    bf16x8 a[2], b[4];
#pragma unroll
    for (int m = 0; m < 2; ++m)
      a[m] = *(const bf16x8*)(As + (wv * 32 + m * 16 + lr) * 72 + ks * 32 + kg * 8);
#pragma unroll
    for (int j = 0; j < 4; ++j)
      b[j] = *(const bf16x8*)(Bs + (j * 16 + lr) * 72 + ks * 32 + kg * 8);
#pragma unroll
    for (int m = 0; m < 2; ++m)
#pragma unroll
      for (int j = 0; j < 4; ++j)
        acc[m][j] = __builtin_amdgcn_mfma_f32_16x16x32_bf16(a[m], b[j], acc[m][j], 0, 0, 0);
  }

  float* cs = &Cs[wv][0];
#pragma unroll
  for (int m = 0; m < 2; ++m)
#pragma unroll
    for (int j = 0; j < 4; ++j)
#pragma unroll
      for (int q = 0; q < 4; ++q)
        cs[(m * 16 + kg * 4 + q) * 68 + j * 16 + lr] = acc[m][j][q];
  __syncthreads();

  const int row = lane & 31, half = lane >> 5;
  const int rg = n0 + wv * 32 + row;
  if (rg < NN) {
    const float* rp = cs + row * 68 + half * 32;
    ushort ob[32];
#pragma unroll
    for (int t = 0; t < 32; ++t) ob[t] = f2bf(rp[t]);
    ushort* op = g + (size_t)rg * 512 + c * 64 + half * 32;
#pragma unroll
    for (int t = 0; t < 4; ++t)
      *(uint4*)(op + t * 8) = *(uint4*)(ob + t * 8);
  }
}

// ---------------- CSR build: histogram -> 2-kernel scan -> fill --------------
__global__ void hist_kernel(const int* __restrict__ dst, int* __restrict__ cnt) {
  int e = blockIdx.x * 256 + threadIdx.x;
  if (e < NE) atomicAdd(&cnt[dst[e]], 1);
}

// per-1024-chunk totals
__global__ __launch_bounds__(1024) void scan1_kernel(const int* __restrict__ cnt,
                                                     int* __restrict__ blocksum) {
  __shared__ int ws[16];
  int tid = threadIdx.x, t = blockIdx.x * 1024 + tid;
  int v = (t < NN) ? cnt[t] : 0;
#pragma unroll
  for (int off = 32; off; off >>= 1) v += __shfl_xor(v, off);
  if ((tid & 63) == 0) ws[tid >> 6] = v;
  __syncthreads();
  if (tid < 16) {
    int s = ws[tid];
#pragma unroll
    for (int off = 8; off; off >>= 1) s += __shfl_xor(s, off, 16);
    if (tid == 0) blocksum[blockIdx.x] = s;
  }
}

// full per-chunk exclusive scan; each block derives its own chunk offset from
// the 49 blocksums in-register (scan2 fused away).
__global__ __launch_bounds__(1024) void scan3_kernel(const int* __restrict__ blocksum,
                                                     int* __restrict__ cntcur,
                                                     int* __restrict__ rowptr) {
  __shared__ int ws[16];
  __shared__ int boff;
  int tid = threadIdx.x, lane = tid & 63, wv = tid >> 6;
  if (wv == 0) {
    int v = (lane < SCAN_BLOCKS && lane < (int)blockIdx.x) ? blocksum[lane] : 0;
#pragma unroll
    for (int off = 32; off; off >>= 1) v += __shfl_xor(v, off);
    if (lane == 0) boff = v;  // sum of blocksum[0..bid-1]
  }
  int t = blockIdx.x * 1024 + tid;
  int orig = (t < NN) ? cntcur[t] : 0;
  int v = orig;
#pragma unroll
  for (int off = 1; off < 64; off <<= 1) {
    int u = __shfl_up(v, off);
    if (lane >= off) v += u;
  }
  if (lane == 63) ws[wv] = v;
  __syncthreads();
  if (tid < 16) {
    int s = ws[tid];
#pragma unroll
    for (int off = 1; off < 16; off <<= 1) {
      int u = __shfl_up(s, off, 16);
      if (tid >= off) s += u;
    }
    ws[tid] = s;
  }
  __syncthreads();
  if (t < NN) {
    int excl = boff + (wv ? ws[wv - 1] : 0) + (v - orig);
    rowptr[t] = excl;
    cntcur[t] = excl;
  }
  if (blockIdx.x == SCAN_BLOCKS - 1 && tid == 0) rowptr[NN] = boff + ws[15];
}

// fill: CSR payload = src node + omega row packed f16x8
__global__ void fill_kernel(const int* __restrict__ dst, const int* __restrict__ src,
                            const float* __restrict__ omega, int* __restrict__ cursor,
                            int* __restrict__ esrc, uint4* __restrict__ eom) {
  int e = blockIdx.x * 256 + threadIdx.x;
  if (e < NE) {
    int d = dst[e];
    int pos = atomicAdd(&cursor[d], 1);
    esrc[pos] = src[e];
    const float4* om4 = (const float4*)(omega + (size_t)e * 8);
    float4 o0 = om4[0], o1 = om4[1];
    union { _Float16 f[8]; uint4 v; } pk;
    pk.f[0] = (_Float16)o0.x; pk.f[1] = (_Float16)o0.y;
    pk.f[2] = (_Float16)o0.z; pk.f[3] = (_Float16)o0.w;
    pk.f[4] = (_Float16)o1.x; pk.f[5] = (_Float16)o1.y;
    pk.f[6] = (_Float16)o1.z; pk.f[7] = (_Float16)o1.w;
    eom[pos] = pk.v;
  }
}

// ---------------- conv + LayerNorm (+ReLU) fused, 8x-unrolled gather ---------
// out[n,c,:] = LN( sum_{e in in(n)} omega[e,c] * g[src_e, c, :] )
// Node-major table (R8 structure): one wave per node, 1 KB coalesced gather
// per edge, 8 edges in flight. Proven fabric-bound at ~4.1 TB/s.
template <bool RELU, bool BF16OUT>
__global__ __launch_bounds__(256) void conv_ln_kernel(
    const ushort* __restrict__ g, const int* __restrict__ esrc,
    const uint* __restrict__ eomw, const int* __restrict__ rowptr,
    const float* __restrict__ gamma, const float* __restrict__ beta,
    void* __restrict__ outv) {
  int n = blockIdx.x * 4 + (threadIdx.x >> 6);
  if (n >= NN) return;
  const int lane = threadIdx.x & 63;
  const int c = lane >> 3;          // channel of this lane
  const int hi = c & 1;             // which half of the omega word
  const int cw = c >> 1;            // omega word index within the edge's 16B
  const int i0 = (lane & 7) * 8;    // H-offset of this lane's 8 elements
  int start = rowptr[n], end = rowptr[n + 1];
  const uint4* g4 = (const uint4*)g;
  float acc[8] = {0.f, 0.f, 0.f, 0.f, 0.f, 0.f, 0.f, 0.f};

  int idx = start;
  // 8x unroll: 8 independent 1KB gathers in flight per wave
  for (; idx + 7 < end; idx += 8) {
    int s0 = esrc[idx + 0], s1 = esrc[idx + 1], s2 = esrc[idx + 2], s3 = esrc[idx + 3];
    int s4 = esrc[idx + 4], s5 = esrc[idx + 5], s6 = esrc[idx + 6], s7 = esrc[idx + 7];
    uint4 h0 = g4[(size_t)s0 * 64 + lane];
    uint4 h1 = g4[(size_t)s1 * 64 + lane];
    uint4 h2 = g4[(size_t)s2 * 64 + lane];
    uint4 h3 = g4[(size_t)s3 * 64 + lane];
    uint4 h4 = g4[(size_t)s4 * 64 + lane];
    uint4 h5 = g4[(size_t)s5 * 64 + lane];
    uint4 h6 = g4[(size_t)s6 * 64 + lane];
    uint4 h7 = g4[(size_t)s7 * 64 + lane];
    float w0 = omw_decode(eomw[(idx + 0) * 4 + cw], hi);
    float w1 = omw_decode(eomw[(idx + 1) * 4 + cw], hi);
    float w2 = omw_decode(eomw[(idx + 2) * 4 + cw], hi);
    float w3 = omw_decode(eomw[(idx + 3) * 4 + cw], hi);
    float w4 = omw_decode(eomw[(idx + 4) * 4 + cw], hi);
    float w5 = omw_decode(eomw[(idx + 5) * 4 + cw], hi);
    float w6 = omw_decode(eomw[(idx + 6) * 4 + cw], hi);
    float w7 = omw_decode(eomw[(idx + 7) * 4 + cw], hi);
    acc8(acc, h0, w0); acc8(acc, h1, w1); acc8(acc, h2, w2); acc8(acc, h3, w3);
    acc8(acc, h4, w4); acc8(acc, h5, w5); acc8(acc, h6, w6); acc8(acc, h7, w7);
  }
  for (; idx + 3 < end; idx += 4) {
    int s0 = esrc[idx + 0], s1 = esrc[idx + 1], s2 = esrc[idx + 2], s3 = esrc[idx + 3];
    uint4 h0 = g4[(size_t)s0 * 64 + lane];
    uint4 h1 = g4[(size_t)s1 * 64 + lane];
    uint4 h2 = g4[(size_t)s2 * 64 + lane];
    uint4 h3 = g4[(size_t)s3 * 64 + lane];
    float w0 = omw_decode(eomw[(idx + 0) * 4 + cw], hi);
    float w1 = omw_decode(eomw[(idx + 1) * 4 + cw], hi);
    float w2 = omw_decode(eomw[(idx + 2) * 4 + cw], hi);
    float w3 = omw_decode(eomw[(idx + 3) * 4 + cw], hi);
    acc8(acc, h0, w0); acc8(acc, h1, w1); acc8(acc, h2, w2); acc8(acc, h3, w3);
  }
  for (; idx < end; ++idx) {
    int s = esrc[idx];
    uint4 hv = g4[(size_t)s * 64 + lane];
    acc8(acc, hv, omw_decode(eomw[idx * 4 + cw], hi));
  }

  // LayerNorm over the 64 H-values of channel c (8 lanes x 8 each)
  float s8 = ((acc[0] + acc[1]) + (acc[2] + acc[3])) +
             ((acc[4] + acc[5]) + (acc[6] + acc[7]));
  s8 += __shfl_xor(s8, 1);
  s8 += __shfl_xor(s8, 2);
  s8 += __shfl_xor(s8, 4);
  float mu = s8 * (1.f / 64.f);
  float d[8];
  float v = 0.f;
#pragma unroll
  for (int j = 0; j < 8; ++j) {
    d[j] = acc[j] - mu;
    v += d[j] * d[j];
  }
  v += __shfl_xor(v, 1);
  v += __shfl_xor(v, 2);
  v += __shfl_xor(v, 4);
  float inv = rsqrtf(v * (1.f / 64.f) + LN_EPS);
  float4 g0 = *(const float4*)(gamma + i0);
  float4 g1 = *(const float4*)(gamma + i0 + 4);
  float4 b0 = *(const float4*)(beta + i0);
  float4 b1 = *(const float4*)(beta + i0 + 4);
  float gg[8] = {g0.x, g0.y, g0.z, g0.w, g1.x, g1.y, g1.z, g1.w};
  float bb[8] = {b0.x, b0.y, b0.z, b0.w, b1.x, b1.y, b1.z, b1.w};
  float y[8];
#pragma unroll
  for (int j = 0; j < 8; ++j) {
    float t = d[j] * inv * gg[j] + bb[j];
    y[j] = RELU ? fmaxf(t, 0.f) : t;
  }
  if (BF16OUT) {
    ushort o[8];
#pragma unroll
    for (int j = 0; j < 8; ++j) o[j] = f2bf(y[j]);
    *(uint4*)((ushort*)outv + (size_t)n * 512 + c * 64 + i0) = *(uint4*)o;
  } else {
    float* op = (float*)outv + (size_t)n * 512 + c * 64 + i0;
    *(float4*)op = make_float4(y[0], y[1], y[2], y[3]);
    *(float4*)(op + 4) = make_float4(y[4], y[5], y[6], y[7]);
  }
}

extern "C" void kernel_launch(void* const* d_in, const int* in_sizes, int n_in,
                              void* d_out, int out_size, void* d_ws, size_t ws_size,
                              hipStream_t stream) {
  const float* x     = (const float*)d_in[0];
  const int*   edge  = (const int*)d_in[1];   // [2,E]: src then dst
  const float* omega = (const float*)d_in[2]; // [E,8]
  const float* proj  = (const float*)d_in[3]; // [256,512]
  const float* W1    = (const float*)d_in[4]; // [8,64,64]
  const float* W2    = (const float*)d_in[5];
  const float* gamma = (const float*)d_in[6];
  const float* beta  = (const float*)d_in[7];
  const int* src = edge;
  const int* dst = edge + NE;

  // ws layout (16B-aligned): hbf | eom | esrc | rowptr | cntcur | blocksum | projW1T | W2T
  char* p = (char*)d_ws;
  ushort* hbf    = (ushort*)p;              p += (size_t)NN * CHW * 2;   // 51.2 MB
  uint4*  eom    = (uint4*)p;               p += (size_t)NE * 16;        // 12.8 MB
  int*    esrc   = (int*)p;                 p += (size_t)NE * 4;         // 3.2 MB
  int*    rowptr = (int*)p;                 p += (size_t)(NN + 16) * 4;
  int*    cntcur = (int*)p;                 p += (size_t)(NN + 16) * 4;
  int*    blocksum=(int*)p;                 p += (size_t)64 * 4;
  ushort* projW1T= (ushort*)p;              p += (size_t)512 * 256 * 2;
  ushort* W2T    = (ushort*)p;

  ushort* h1 = (ushort*)d_out;  // h1 bf16 in d_out's first half (dead before
                                // the final f32 write overwrites it)

  // ---- CSR build ----
  hipMemsetAsync(cntcur, 0, NN * sizeof(int), stream);
  hist_kernel<<<(NE + 255) / 256, 256, 0, stream>>>(dst, cntcur);
  scan1_kernel<<<SCAN_BLOCKS, 1024, 0, stream>>>(cntcur, blocksum);
  scan3_kernel<<<SCAN_BLOCKS, 1024, 0, stream>>>(blocksum, cntcur, rowptr);
  fill_kernel<<<(NE + 255) / 256, 256, 0, stream>>>(dst, src, omega, cntcur, esrc, eom);

  // ---- parameter prep ----
  fold_w1_kernel<<<512, 256, 0, stream>>>(proj, W1, projW1T);
  w2t_kernel<<<8, 256, 0, stream>>>(W2, W2T);

  // ---- layer 0: g1 = x @ projW1  ->  h1 = ReLU(LN(gather(g1))) ----
  gemm_proj_kernel<<<dim3((NN + 127) / 128, 4), 256, 0, stream>>>(x, projW1T, hbf);
  conv_ln_kernel<true, true><<<(NN + 3) / 4, 256, 0, stream>>>(
      hbf, esrc, (const uint*)eom, rowptr, gamma, beta, h1);

  // ---- layer 1: g2 = h1 @ W2  ->  out = LN(gather(g2)) ----
  bmm_g_kernel<<<dim3((NN + 127) / 128, CC), 256, 0, stream>>>(h1, W2T, hbf);
  conv_ln_kernel<false, false><<<(NN + 3) / 4, 256, 0, stream>>>(
      hbf, esrc, (const uint*)eom, rowptr, gamma, beta, d_out);
}